// Round 10
// baseline (246.676 us; speedup 1.0000x reference)
//
#include <hip/hip_runtime.h>
#include <hip/hip_bf16.h>

#define HEADS 8
#define DHEAD 64
#define CDIM  512
#define SEQ   2304      // 48*48
#define ND    512       // HEADS*DHEAD
#define NCHUNK 6        // split-K chunks over the 36 key-tiles

typedef unsigned short u16;
typedef unsigned int   u32;
typedef __attribute__((ext_vector_type(8))) short short8;
typedef __attribute__((ext_vector_type(4))) float f32x4;

#define QSCALE 0.18033688011112043f   // 0.125 * log2(e): folded into Q so softmax is exp2

__device__ __forceinline__ u16 f2bf(float f) {
    union { float f; u32 u; } x; x.f = f;
    u32 r = x.u + 0x7FFFu + ((x.u >> 16) & 1u);   // RNE
    return (u16)(r >> 16);
}
__device__ __forceinline__ float bf2f(u16 v) {
    union { u32 u; float f; } x; x.u = ((u32)v) << 16; return x.f;
}
// pack two f32 -> two bf16 in one u32 (round-half-up via +0x8000, then v_perm byte-select)
__device__ __forceinline__ u32 pkbf(float a, float b) {
    union { float f; u32 u; } x, y; x.f = a; y.f = b;
    return __builtin_amdgcn_perm(y.u + 0x8000u, x.u + 0x8000u, 0x07060302u);
}
__device__ __forceinline__ f32x4 mfma16(short8 a, short8 b, f32x4 c) {
    return __builtin_amdgcn_mfma_f32_16x16x32_bf16(a, b, c, 0, 0, 0);
}
// async 16B global->LDS (wave-uniform base + lane*16 dest)
__device__ __forceinline__ void cp16(const void* g, void* l) {
    __builtin_amdgcn_global_load_lds(
        (const __attribute__((address_space(1))) u32*)(uintptr_t)g,
        (__attribute__((address_space(3))) u32*)(u32)(uintptr_t)l,
        16, 0, 0);
}
// LDS K-slot r holds source K row kperm_inv(r), so post-softmax P sits in PV B-frag order.
__device__ __forceinline__ int kperm_inv(int r) {
    return (r & ~0x1C) | ((r & 0x0C) << 1) | ((r & 0x10) >> 2);
}

// ---------------- fused: weight convert (float4-vectorized) + x transpose
__global__ void prep_kernel(const float* __restrict__ H,
                            const float* __restrict__ Wq, const float* __restrict__ Wk,
                            const float* __restrict__ Wv, const float* __restrict__ Wo,
                            u16* __restrict__ Wqkv, u16* __restrict__ Wob,
                            u16* __restrict__ X) {
    __shared__ float tile[32][33];
    const int t = threadIdx.x;
    const int bx = blockIdx.x;
    if (bx < 1024) {
        const int N1 = CDIM * ND;                 // 262144
        int i4 = (bx * 256 + t) * 4;
        float4 v;
        if (i4 < N1)             v = *(const float4*)&Wq[i4];
        else if (i4 < 2 * N1)    v = *(const float4*)&Wk[i4 - N1];
        else if (i4 < 3 * N1)    v = *(const float4*)&Wv[i4 - 2 * N1];
        else                     v = *(const float4*)&Wo[i4 - 3 * N1];
        uint2 o;
        o.x = pkbf(v.x, v.y);
        o.y = pkbf(v.z, v.w);
        u16* d = (i4 < 3 * N1) ? &Wqkv[i4] : &Wob[i4 - 3 * N1];
        *(uint2*)d = o;
    } else {
        int bb = bx - 1024;                       // 0..2303
        int st = bb % 72, ct = (bb / 72) % 16, b = bb / (72 * 16);
        int tx = t & 31, ty = t >> 5;
#pragma unroll
        for (int k = 0; k < 4; ++k) {
            int c = ct * 32 + ty + k * 8;
            tile[ty + k * 8][tx] = H[((size_t)b * CDIM + c) * SEQ + st * 32 + tx];
        }
        __syncthreads();
#pragma unroll
        for (int k = 0; k < 4; ++k) {
            int s = st * 32 + ty + k * 8;
            X[((size_t)b * SEQ + s) * CDIM + ct * 32 + tx] = f2bf(tile[tx][ty + k * 8]);
        }
    }
}

// ---------------- QKV projection GEMM (NT), 64x128 tiles, double-buffered async staging
__global__ __launch_bounds__(256) void gemm_qkv_kernel(
        const u16* __restrict__ W, const u16* __restrict__ X,
        const float* __restrict__ bq, const float* __restrict__ bk, const float* __restrict__ bv,
        u16* __restrict__ Q, u16* __restrict__ K, u16* __restrict__ V) {
    __shared__ __align__(16) u16 sm[2 * (64 * 64 + 128 * 64)];   // 48 KB: [buf][As|Bs]
    const int n0 = blockIdx.x * 128;
    const int m0 = blockIdx.y * 64;
    const int b  = blockIdx.z;
    const int t = threadIdx.x;
    const int lane = t & 63, w = t >> 6;
    const int l16 = lane & 15, quad = lane >> 4;
    const int x7 = l16 & 7;
    const int srow = t >> 3, scol = (t & 7) * 8;
    const int scol_sw = ((t & 7) ^ (srow & 7)) * 8;   // swizzled source chunk
    const u16* Xb = X + (size_t)b * SEQ * CDIM;

    f32x4 acc[4][2] = {};

    // preload kb=0 into buf 0
    {
        u16* As = sm; u16* Bs = sm + 4096;
#pragma unroll
        for (int it = 0; it < 2; ++it) {
            int r2 = it * 32 + srow;
            cp16(&W[(size_t)(m0 + r2) * 512 + scol_sw], &As[r2 * 64 + scol]);
        }
#pragma unroll
        for (int it = 0; it < 4; ++it) {
            int r2 = it * 32 + srow;
            cp16(&Xb[(size_t)(n0 + r2) * 512 + scol_sw], &Bs[r2 * 64 + scol]);
        }
    }
    for (int kb = 0; kb < 512; kb += 64) {
        const int pb = (kb >> 6) & 1;
        const u16* As = sm + pb * 12288;
        const u16* Bs = As + 4096;
        __syncthreads();                               // buf pb ready (vmcnt drain)
        if (kb + 64 < 512) {                           // prefetch next into buf pb^1
            u16* An = sm + (pb ^ 1) * 12288;
            u16* Bn = An + 4096;
#pragma unroll
            for (int it = 0; it < 2; ++it) {
                int r2 = it * 32 + srow;
                cp16(&W[(size_t)(m0 + r2) * 512 + kb + 64 + scol_sw], &An[r2 * 64 + scol]);
            }
#pragma unroll
            for (int it = 0; it < 4; ++it) {
                int r2 = it * 32 + srow;
                cp16(&Xb[(size_t)(n0 + r2) * 512 + kb + 64 + scol_sw], &Bn[r2 * 64 + scol]);
            }
        }
#pragma unroll
        for (int kk = 0; kk < 2; ++kk) {
            const int co = ((kk * 4 + quad) ^ x7) * 8;
            short8 af[4], bfr[2];
#pragma unroll
            for (int i = 0; i < 4; ++i)
                af[i] = *(const short8*)&As[(i * 16 + l16) * 64 + co];
#pragma unroll
            for (int j = 0; j < 2; ++j)
                bfr[j] = *(const short8*)&Bs[(w * 32 + j * 16 + l16) * 64 + co];
#pragma unroll
            for (int i = 0; i < 4; ++i)
#pragma unroll
                for (int j = 0; j < 2; ++j)
                    acc[i][j] = mfma16(af[i], bfr[j], acc[i][j]);
        }
    }

    if (m0 < 1024) {
        const bool isQ = (m0 < 512);
        const float* bias = isQ ? bq : bk;
        const float sc = isQ ? QSCALE : 1.0f;
        const int mq = isQ ? m0 : m0 - 512;
        u16* dst = isQ ? Q : K;
#pragma unroll
        for (int j = 0; j < 2; ++j) {
            int s = n0 + w * 32 + j * 16 + l16;
#pragma unroll
            for (int i = 0; i < 4; ++i) {
                int mm = mq + i * 16 + quad * 4;
                uint2 val;
                val.x = pkbf((acc[i][j][0] + bias[mm + 0]) * sc, (acc[i][j][1] + bias[mm + 1]) * sc);
                val.y = pkbf((acc[i][j][2] + bias[mm + 2]) * sc, (acc[i][j][3] + bias[mm + 3]) * sc);
                *(uint2*)&dst[(((size_t)(b * 8 + (mm >> 6))) * SEQ + s) * 64 + (mm & 63)] = val;
            }
        }
    } else {
#pragma unroll
        for (int j = 0; j < 2; ++j) {
            int s = n0 + w * 32 + j * 16 + l16;
#pragma unroll
            for (int i = 0; i < 4; ++i) {
                int mbase = m0 - 1024 + i * 16 + quad * 4;
#pragma unroll
                for (int r = 0; r < 4; ++r) {
                    int mm = mbase + r;
                    V[((size_t)(b * 512 + mm)) * SEQ + s] = f2bf(acc[i][j][r] + bv[mm]);
                }
            }
        }
    }
}

// ---------------- flash attention partial (split-K x6), 192-q blocks (3 groups), 2-buf dbuf
__global__ __launch_bounds__(256, 5) void attn_partial(
        const u16* __restrict__ Q,    // [16][2304][64] (pre-scaled by QSCALE)
        const u16* __restrict__ K,    // [16][2304][64]
        const u16* __restrict__ Vt,   // [B][512][2304]
        u16* __restrict__ Opart,      // [6*16][2304][64] chunk-normalized bf16
        float* __restrict__ Lpart) {  // [6*16][2304]
    __shared__ __align__(16) u16 sm[2 * 8192];      // 32 KB: [buf][Ks|Vs], each 64x64
    const int pair = blockIdx.x & 15, qt = blockIdx.x >> 4;   // qt 0..11 (192-q tiles)
    const int c = blockIdx.y;                                  // chunk 0..5
    const int b = pair >> 3, h = pair & 7;
    const int t = threadIdx.x, lane = t & 63, w = t >> 6;
    const int l16 = lane & 15, quad = lane >> 4;
    const int x7 = l16 & 7;
    const int srow = t >> 3;
    const int scol = (t & 7) * 8;
    const int scol_sw = ((t & 7) ^ (srow & 7)) * 8;
    const int kinv0 = kperm_inv(srow), kinv1 = kperm_inv(32 + srow);
    const int cA = (quad ^ x7) * 8;        // swizzled chunk for logical chunk quad
    const int cB = (quad ^ x7 ^ 4) * 8;    // swizzled chunk for logical chunk quad+4

    // Q fragments for three q-groups (B-frag: n=q, k=d)
    const u16* Qg = Q + ((size_t)pair * SEQ + qt * 192) * 64;
    const int rA = w * 16 + l16;
    short8 qf[3][2];
#pragma unroll
    for (int G = 0; G < 3; ++G) {
        qf[G][0] = *(const short8*)&Qg[(size_t)(G * 64 + rA) * 64 + quad * 8];
        qf[G][1] = *(const short8*)&Qg[(size_t)(G * 64 + rA) * 64 + 32 + quad * 8];
    }

    const u16* Kg = K  + ((size_t)pair * SEQ + c * 384) * 64;   // 6 tiles of 64 keys
    const u16* Vg = Vt + ((size_t)(b * 512 + h * 64)) * SEQ + c * 384;

    float lacc[3] = {0.f, 0.f, 0.f};
    f32x4 o[3][4] = {};

    // preload kt=0 into buf 0
    {
        u16* Ks = sm; u16* Vs = sm + 4096;
        cp16(&Kg[(size_t)kinv0 * 64 + scol_sw], &Ks[srow * 64 + scol]);
        cp16(&Kg[(size_t)kinv1 * 64 + scol_sw], &Ks[(32 + srow) * 64 + scol]);
        cp16(&Vg[(size_t)srow * SEQ + scol_sw],        &Vs[srow * 64 + scol]);
        cp16(&Vg[(size_t)(32 + srow) * SEQ + scol_sw], &Vs[(32 + srow) * 64 + scol]);
    }
    for (int kt = 0; kt < 6; ++kt) {
        const int pb = kt & 1;
        const u16* Ks = sm + pb * 8192;
        const u16* Vs = Ks + 4096;
        __syncthreads();                              // buf pb ready (vmcnt drain)
        if (kt < 5) {                                 // prefetch kt+1 into buf pb^1
            u16* Kn = sm + (pb ^ 1) * 8192;
            u16* Vn = Kn + 4096;
            cp16(&Kg[(size_t)((kt + 1) * 64 + kinv0) * 64 + scol_sw], &Kn[srow * 64 + scol]);
            cp16(&Kg[(size_t)((kt + 1) * 64 + kinv1) * 64 + scol_sw], &Kn[(32 + srow) * 64 + scol]);
            cp16(&Vg[(size_t)srow * SEQ + (kt + 1) * 64 + scol_sw],        &Vn[srow * 64 + scol]);
            cp16(&Vg[(size_t)(32 + srow) * SEQ + (kt + 1) * 64 + scol_sw], &Vn[(32 + srow) * 64 + scol]);
        }
        // S^T = K Q^T : rows = ki (kperm'd), cols = q; each kf read feeds 3 MFMAs
        f32x4 sacc[3][4];
#pragma unroll
        for (int j = 0; j < 4; ++j) {
            short8 kf0 = *(const short8*)&Ks[(j * 16 + l16) * 64 + cA];
            short8 kf1 = *(const short8*)&Ks[(j * 16 + l16) * 64 + cB];
#pragma unroll
            for (int G = 0; G < 3; ++G) {
                f32x4 z = {0.f, 0.f, 0.f, 0.f};
                z = mfma16(kf0, qf[G][0], z);
                sacc[G][j] = mfma16(kf1, qf[G][1], z);
            }
        }
        // fixed-max softmax; pack P to bf16 immediately
        u32 pk[3][8];
#pragma unroll
        for (int G = 0; G < 3; ++G)
#pragma unroll
            for (int j = 0; j < 4; ++j) {
                float e0 = __builtin_amdgcn_exp2f(sacc[G][j][0]);
                float e1 = __builtin_amdgcn_exp2f(sacc[G][j][1]);
                float e2 = __builtin_amdgcn_exp2f(sacc[G][j][2]);
                float e3 = __builtin_amdgcn_exp2f(sacc[G][j][3]);
                lacc[G] += (e0 + e1) + (e2 + e3);
                pk[G][2 * j]     = pkbf(e0, e1);
                pk[G][2 * j + 1] = pkbf(e2, e3);
            }
        // PV: P already in B-frag order thanks to kperm; each vf read feeds 3 MFMAs
#pragma unroll
        for (int g = 0; g < 2; ++g) {
            const int cg = g ? cB : cA;
#pragma unroll
            for (int i = 0; i < 4; ++i) {
                short8 vf = *(const short8*)&Vs[(i * 16 + l16) * 64 + cg];
#pragma unroll
                for (int G = 0; G < 3; ++G) {
                    short8 pf;
                    u32* pw = (u32*)&pf;
                    pw[0] = pk[G][4 * g + 0];
                    pw[1] = pk[G][4 * g + 1];
                    pw[2] = pk[G][4 * g + 2];
                    pw[3] = pk[G][4 * g + 3];
                    o[G][i] = mfma16(vf, pf, o[G][i]);
                }
            }
        }
    }
    // reduce l across quads (lane's q = l16 within group)
    float linv[3];
#pragma unroll
    for (int G = 0; G < 3; ++G) {
        float lr = lacc[G];
        lr += __shfl_xor(lr, 16);
        lr += __shfl_xor(lr, 32);
        if (quad == 0) Lpart[((size_t)(c * 16 + pair)) * SEQ + qt * 192 + G * 64 + rA] = lr;
        linv[G] = 1.0f / lr;
    }
    const size_t orow = ((size_t)(c * 16 + pair)) * SEQ + qt * 192;

    // single merged bounce: 192 rows x 72 stride (13824 u16 fits the 16384-u16 LDS)
    __syncthreads();
#pragma unroll
    for (int G = 0; G < 3; ++G)
#pragma unroll
        for (int i = 0; i < 4; ++i) {
            uint2 pkv;
            pkv.x = pkbf(o[G][i][0] * linv[G], o[G][i][1] * linv[G]);
            pkv.y = pkbf(o[G][i][2] * linv[G], o[G][i][3] * linv[G]);
            *(uint2*)&sm[(G * 64 + rA) * 72 + i * 16 + quad * 4] = pkv;
        }
    __syncthreads();
#pragma unroll
    for (int it = 0; it < 6; ++it) {
        int v = it * 256 + t;
        int row = v >> 3, col = (v & 7) * 8;
        *(uint4*)&Opart[(orow + row) * 64 + col] = *(const uint4*)&sm[row * 72 + col];
    }
}

// ---------------- combine split-K partials -> At [B][2304][512] bf16
__global__ __launch_bounds__(256) void attn_combine(
        const u16* __restrict__ Opart, const float* __restrict__ Lpart,
        u16* __restrict__ At) {
    const int bid = blockIdx.x;
    const int pair = bid / 144, sb = bid % 144;
    const int tid = threadIdx.x;
    const int rl = tid >> 4, dg = tid & 15;
    const int s = sb * 16 + rl;
    const int b = pair >> 3, h = pair & 7;
    float wc[NCHUNK], L = 0.f;
#pragma unroll
    for (int c = 0; c < NCHUNK; ++c) {
        wc[c] = Lpart[(size_t)(c * 16 + pair) * SEQ + s];
        L += wc[c];
    }
    float invL = 1.0f / L;
    float acc[4] = {0.f, 0.f, 0.f, 0.f};
#pragma unroll
    for (int c = 0; c < NCHUNK; ++c) {
        ushort4 v = *(const ushort4*)&Opart[((size_t)(c * 16 + pair) * SEQ + s) * 64 + dg * 4];
        acc[0] += wc[c] * bf2f(v.x);
        acc[1] += wc[c] * bf2f(v.y);
        acc[2] += wc[c] * bf2f(v.z);
        acc[3] += wc[c] * bf2f(v.w);
    }
    uint2 outv;
    outv.x = pkbf(acc[0] * invL, acc[1] * invL);
    outv.y = pkbf(acc[2] * invL, acc[3] * invL);
    *(uint2*)&At[((size_t)b * SEQ + s) * ND + h * 64 + dg * 4] = outv;
}

// ---------------- output projection GEMM (NT), 64x64 tiles, dbuf async staging
__global__ __launch_bounds__(256) void gemm_out_kernel(
        const u16* __restrict__ Wob, const u16* __restrict__ At,
        const float* __restrict__ bo, float* __restrict__ out) {
    __shared__ __align__(16) u16 sm[2 * 8192];       // 32 KB: [buf][As|Bs], each 64x64
    const int n0 = blockIdx.x * 64;
    const int m0 = blockIdx.y * 64;
    const int b  = blockIdx.z;
    const int t = threadIdx.x;
    const int lane = t & 63, w = t >> 6;
    const int l16 = lane & 15, quad = lane >> 4;
    const int x7 = l16 & 7;
    const int srow = t >> 3, scol = (t & 7) * 8;
    const int scol_sw = ((t & 7) ^ (srow & 7)) * 8;
    const u16* Ab = At + (size_t)b * SEQ * ND;

    f32x4 acc[4] = {};

    {
        u16* As = sm; u16* Bs = sm + 4096;
#pragma unroll
        for (int it = 0; it < 2; ++it) {
            int r2 = it * 32 + srow;
            cp16(&Wob[(size_t)(m0 + r2) * 512 + scol_sw], &As[r2 * 64 + scol]);
            cp16(&Ab [(size_t)(n0 + r2) * 512 + scol_sw], &Bs[r2 * 64 + scol]);
        }
    }
    for (int kb = 0; kb < 512; kb += 64) {
        const int pb = (kb >> 6) & 1;
        const u16* As = sm + pb * 8192;
        const u16* Bs = As + 4096;
        __syncthreads();
        if (kb + 64 < 512) {
            u16* An = sm + (pb ^ 1) * 8192;
            u16* Bn = An + 4096;
#pragma unroll
            for (int it = 0; it < 2; ++it) {
                int r2 = it * 32 + srow;
                cp16(&Wob[(size_t)(m0 + r2) * 512 + kb + 64 + scol_sw], &An[r2 * 64 + scol]);
                cp16(&Ab [(size_t)(n0 + r2) * 512 + kb + 64 + scol_sw], &Bn[r2 * 64 + scol]);
            }
        }
#pragma unroll
        for (int kk = 0; kk < 2; ++kk) {
            const int co = ((kk * 4 + quad) ^ x7) * 8;
            short8 af[4];
#pragma unroll
            for (int i = 0; i < 4; ++i)
                af[i] = *(const short8*)&As[(i * 16 + l16) * 64 + co];
            short8 bfr = *(const short8*)&Bs[(w * 16 + l16) * 64 + co];
#pragma unroll
            for (int i = 0; i < 4; ++i)
                acc[i] = mfma16(af[i], bfr, acc[i]);
        }
    }
#pragma unroll
    for (int i = 0; i < 4; ++i) {
        int cbase = m0 + i * 16 + quad * 4;
        int s = n0 + w * 16 + l16;
#pragma unroll
        for (int r = 0; r < 4; ++r) {
            int cc = cbase + r;
            __builtin_nontemporal_store(acc[i][r] + bo[cc],
                                        &out[((size_t)(b * 512 + cc)) * SEQ + s]);
        }
    }
}

extern "C" void kernel_launch(void* const* d_in, const int* in_sizes, int n_in,
                              void* d_out, int out_size, void* d_ws, size_t ws_size,
                              hipStream_t stream) {
    const float* H  = (const float*)d_in[0];
    const float* Wq = (const float*)d_in[1];
    const float* bq = (const float*)d_in[2];
    const float* Wk = (const float*)d_in[3];
    const float* bk = (const float*)d_in[4];
    const float* Wv = (const float*)d_in[5];
    const float* bv = (const float*)d_in[6];
    const float* Wo = (const float*)d_in[7];
    const float* bo = (const float*)d_in[8];
    float* out = (float*)d_out;

    u16* ws    = (u16*)d_ws;
    u16* Wqkv  = ws;                                  // 1536*512
    u16* Wob   = Wqkv  + 1536 * 512;                  // 512*512
    u16* Xbf   = Wob   + 512 * 512;                   // 2*2304*512
    u16* Qb    = Xbf   + 2 * SEQ * CDIM;              // 16*2304*64
    u16* Kb    = Qb    + 2 * SEQ * ND;
    u16* Vb    = Kb    + 2 * SEQ * ND;
    u16* At    = Vb    + 2 * SEQ * ND;
    u16* Opart = At    + 2 * SEQ * ND;                // 96*2304*64
    float* Lpart = (float*)(Opart + NCHUNK * 16 * SEQ * 64);

    prep_kernel<<<3328, 256, 0, stream>>>(H, Wq, Wk, Wv, Wo, Wqkv, Wob, Xbf);
    gemm_qkv_kernel<<<dim3(18, 24, 2), 256, 0, stream>>>(Wqkv, Xbf, bq, bk, bv, Qb, Kb, Vb);
    attn_partial<<<dim3(192, NCHUNK), 256, 0, stream>>>(Qb, Kb, Vb, Opart, Lpart);
    attn_combine<<<2304, 256, 0, stream>>>(Opart, Lpart, At);
    gemm_out_kernel<<<dim3(36, 8, 2), 256, 0, stream>>>(Wob, At, bo, out);
}

// Round 11
// 134.776 us; speedup vs baseline: 1.8303x; 1.8303x over previous
//
#include <hip/hip_runtime.h>
#include <hip/hip_bf16.h>

#define HEADS 8
#define DHEAD 64
#define CDIM  512
#define SEQ   2304      // 48*48
#define ND    512       // HEADS*DHEAD
#define NCHUNK 4        // split-K chunks over the 36 key-tiles (9 tiles each)

typedef unsigned short u16;
typedef unsigned int   u32;
typedef __attribute__((ext_vector_type(8))) short short8;
typedef __attribute__((ext_vector_type(4))) float f32x4;

#define QSCALE 0.18033688011112043f   // 0.125 * log2(e): folded into Q so softmax is exp2

__device__ __forceinline__ u16 f2bf(float f) {
    union { float f; u32 u; } x; x.f = f;
    u32 r = x.u + 0x7FFFu + ((x.u >> 16) & 1u);   // RNE
    return (u16)(r >> 16);
}
__device__ __forceinline__ float bf2f(u16 v) {
    union { u32 u; float f; } x; x.u = ((u32)v) << 16; return x.f;
}
// pack two f32 -> two bf16 in one u32 (round-half-up via +0x8000, then v_perm byte-select)
__device__ __forceinline__ u32 pkbf(float a, float b) {
    union { float f; u32 u; } x, y; x.f = a; y.f = b;
    return __builtin_amdgcn_perm(y.u + 0x8000u, x.u + 0x8000u, 0x07060302u);
}
__device__ __forceinline__ f32x4 mfma16(short8 a, short8 b, f32x4 c) {
    return __builtin_amdgcn_mfma_f32_16x16x32_bf16(a, b, c, 0, 0, 0);
}
// async 16B global->LDS (wave-uniform base + lane*16 dest)
__device__ __forceinline__ void cp16(const void* g, void* l) {
    __builtin_amdgcn_global_load_lds(
        (const __attribute__((address_space(1))) u32*)(uintptr_t)g,
        (__attribute__((address_space(3))) u32*)(u32)(uintptr_t)l,
        16, 0, 0);
}
// LDS K-slot r holds source K row kperm_inv(r), so post-softmax P sits in PV B-frag order.
__device__ __forceinline__ int kperm_inv(int r) {
    return (r & ~0x1C) | ((r & 0x0C) << 1) | ((r & 0x10) >> 2);
}

// ---------------- fused: weight convert (float4-vectorized) + x transpose
__global__ void prep_kernel(const float* __restrict__ H,
                            const float* __restrict__ Wq, const float* __restrict__ Wk,
                            const float* __restrict__ Wv, const float* __restrict__ Wo,
                            u16* __restrict__ Wqkv, u16* __restrict__ Wob,
                            u16* __restrict__ X) {
    __shared__ float tile[32][33];
    const int t = threadIdx.x;
    const int bx = blockIdx.x;
    if (bx < 1024) {
        const int N1 = CDIM * ND;                 // 262144
        int i4 = (bx * 256 + t) * 4;
        float4 v;
        if (i4 < N1)             v = *(const float4*)&Wq[i4];
        else if (i4 < 2 * N1)    v = *(const float4*)&Wk[i4 - N1];
        else if (i4 < 3 * N1)    v = *(const float4*)&Wv[i4 - 2 * N1];
        else                     v = *(const float4*)&Wo[i4 - 3 * N1];
        uint2 o;
        o.x = pkbf(v.x, v.y);
        o.y = pkbf(v.z, v.w);
        u16* d = (i4 < 3 * N1) ? &Wqkv[i4] : &Wob[i4 - 3 * N1];
        *(uint2*)d = o;
    } else {
        int bb = bx - 1024;                       // 0..2303
        int st = bb % 72, ct = (bb / 72) % 16, b = bb / (72 * 16);
        int tx = t & 31, ty = t >> 5;
#pragma unroll
        for (int k = 0; k < 4; ++k) {
            int c = ct * 32 + ty + k * 8;
            tile[ty + k * 8][tx] = H[((size_t)b * CDIM + c) * SEQ + st * 32 + tx];
        }
        __syncthreads();
#pragma unroll
        for (int k = 0; k < 4; ++k) {
            int s = st * 32 + ty + k * 8;
            X[((size_t)b * SEQ + s) * CDIM + ct * 32 + tx] = f2bf(tile[tx][ty + k * 8]);
        }
    }
}

// ---------------- QKV projection GEMM (NT), 64x128 tiles, double-buffered async staging
__global__ __launch_bounds__(256) void gemm_qkv_kernel(
        const u16* __restrict__ W, const u16* __restrict__ X,
        const float* __restrict__ bq, const float* __restrict__ bk, const float* __restrict__ bv,
        u16* __restrict__ Q, u16* __restrict__ K, u16* __restrict__ V) {
    __shared__ __align__(16) u16 sm[2 * (64 * 64 + 128 * 64)];   // 48 KB: [buf][As|Bs]
    const int n0 = blockIdx.x * 128;
    const int m0 = blockIdx.y * 64;
    const int b  = blockIdx.z;
    const int t = threadIdx.x;
    const int lane = t & 63, w = t >> 6;
    const int l16 = lane & 15, quad = lane >> 4;
    const int x7 = l16 & 7;
    const int srow = t >> 3, scol = (t & 7) * 8;
    const int scol_sw = ((t & 7) ^ (srow & 7)) * 8;   // swizzled source chunk
    const u16* Xb = X + (size_t)b * SEQ * CDIM;

    f32x4 acc[4][2] = {};

    // preload kb=0 into buf 0
    {
        u16* As = sm; u16* Bs = sm + 4096;
#pragma unroll
        for (int it = 0; it < 2; ++it) {
            int r2 = it * 32 + srow;
            cp16(&W[(size_t)(m0 + r2) * 512 + scol_sw], &As[r2 * 64 + scol]);
        }
#pragma unroll
        for (int it = 0; it < 4; ++it) {
            int r2 = it * 32 + srow;
            cp16(&Xb[(size_t)(n0 + r2) * 512 + scol_sw], &Bs[r2 * 64 + scol]);
        }
    }
    for (int kb = 0; kb < 512; kb += 64) {
        const int pb = (kb >> 6) & 1;
        const u16* As = sm + pb * 12288;
        const u16* Bs = As + 4096;
        __syncthreads();                               // buf pb ready (vmcnt drain)
        if (kb + 64 < 512) {                           // prefetch next into buf pb^1
            u16* An = sm + (pb ^ 1) * 12288;
            u16* Bn = An + 4096;
#pragma unroll
            for (int it = 0; it < 2; ++it) {
                int r2 = it * 32 + srow;
                cp16(&W[(size_t)(m0 + r2) * 512 + kb + 64 + scol_sw], &An[r2 * 64 + scol]);
            }
#pragma unroll
            for (int it = 0; it < 4; ++it) {
                int r2 = it * 32 + srow;
                cp16(&Xb[(size_t)(n0 + r2) * 512 + kb + 64 + scol_sw], &Bn[r2 * 64 + scol]);
            }
        }
#pragma unroll
        for (int kk = 0; kk < 2; ++kk) {
            const int co = ((kk * 4 + quad) ^ x7) * 8;
            short8 af[4], bfr[2];
#pragma unroll
            for (int i = 0; i < 4; ++i)
                af[i] = *(const short8*)&As[(i * 16 + l16) * 64 + co];
#pragma unroll
            for (int j = 0; j < 2; ++j)
                bfr[j] = *(const short8*)&Bs[(w * 32 + j * 16 + l16) * 64 + co];
#pragma unroll
            for (int i = 0; i < 4; ++i)
#pragma unroll
                for (int j = 0; j < 2; ++j)
                    acc[i][j] = mfma16(af[i], bfr[j], acc[i][j]);
        }
    }

    if (m0 < 1024) {
        const bool isQ = (m0 < 512);
        const float* bias = isQ ? bq : bk;
        const float sc = isQ ? QSCALE : 1.0f;
        const int mq = isQ ? m0 : m0 - 512;
        u16* dst = isQ ? Q : K;
#pragma unroll
        for (int j = 0; j < 2; ++j) {
            int s = n0 + w * 32 + j * 16 + l16;
#pragma unroll
            for (int i = 0; i < 4; ++i) {
                int mm = mq + i * 16 + quad * 4;
                uint2 val;
                val.x = pkbf((acc[i][j][0] + bias[mm + 0]) * sc, (acc[i][j][1] + bias[mm + 1]) * sc);
                val.y = pkbf((acc[i][j][2] + bias[mm + 2]) * sc, (acc[i][j][3] + bias[mm + 3]) * sc);
                *(uint2*)&dst[(((size_t)(b * 8 + (mm >> 6))) * SEQ + s) * 64 + (mm & 63)] = val;
            }
        }
    } else {
#pragma unroll
        for (int j = 0; j < 2; ++j) {
            int s = n0 + w * 32 + j * 16 + l16;
#pragma unroll
            for (int i = 0; i < 4; ++i) {
                int mbase = m0 - 1024 + i * 16 + quad * 4;
#pragma unroll
                for (int r = 0; r < 4; ++r) {
                    int mm = mbase + r;
                    V[((size_t)(b * 512 + mm)) * SEQ + s] = f2bf(acc[i][j][r] + bv[mm]);
                }
            }
        }
    }
}

// ---------------- flash attention partial (split-K x4), 192-q blocks (3 groups), dbuf K/V
__global__ __launch_bounds__(256, 3) void attn_partial(
        const u16* __restrict__ Q,    // [16][2304][64] (pre-scaled by QSCALE)
        const u16* __restrict__ K,    // [16][2304][64]
        const u16* __restrict__ Vt,   // [B][512][2304]
        u16* __restrict__ Opart,      // [4*16][2304][64] chunk-normalized bf16
        float* __restrict__ Lpart) {  // [4*16][2304]
    __shared__ __align__(16) u16 sm[2 * 8192];      // 32 KB: [buf][Ks|Vs], each 64x64
    const int pair = blockIdx.x & 15, qt = blockIdx.x >> 4;   // qt 0..11 (192-q tiles)
    const int c = blockIdx.y;
    const int b = pair >> 3, h = pair & 7;
    const int t = threadIdx.x, lane = t & 63, w = t >> 6;
    const int l16 = lane & 15, quad = lane >> 4;
    const int x7 = l16 & 7;
    const int srow = t >> 3;
    const int scol = (t & 7) * 8;
    const int scol_sw = ((t & 7) ^ (srow & 7)) * 8;
    const int kinv0 = kperm_inv(srow), kinv1 = kperm_inv(32 + srow);
    const int cA = (quad ^ x7) * 8;        // swizzled chunk for logical chunk quad
    const int cB = (quad ^ x7 ^ 4) * 8;    // swizzled chunk for logical chunk quad+4

    // Q fragments for three q-groups (B-frag: n=q, k=d)
    const u16* Qg = Q + ((size_t)pair * SEQ + qt * 192) * 64;
    const int rA = w * 16 + l16;
    short8 qf[3][2];
#pragma unroll
    for (int G = 0; G < 3; ++G) {
        qf[G][0] = *(const short8*)&Qg[(size_t)(G * 64 + rA) * 64 + quad * 8];
        qf[G][1] = *(const short8*)&Qg[(size_t)(G * 64 + rA) * 64 + 32 + quad * 8];
    }

    const u16* Kg = K  + ((size_t)pair * SEQ + c * 576) * 64;
    const u16* Vg = Vt + ((size_t)(b * 512 + h * 64)) * SEQ + c * 576;

    float lacc[3] = {0.f, 0.f, 0.f};
    f32x4 o[3][4] = {};

    // preload kt=0 into buf 0
    {
        u16* Ks = sm; u16* Vs = sm + 4096;
        cp16(&Kg[(size_t)kinv0 * 64 + scol_sw], &Ks[srow * 64 + scol]);
        cp16(&Kg[(size_t)kinv1 * 64 + scol_sw], &Ks[(32 + srow) * 64 + scol]);
        cp16(&Vg[(size_t)srow * SEQ + scol_sw],        &Vs[srow * 64 + scol]);
        cp16(&Vg[(size_t)(32 + srow) * SEQ + scol_sw], &Vs[(32 + srow) * 64 + scol]);
    }
    for (int kt = 0; kt < 9; ++kt) {
        const int pb = kt & 1;
        const u16* Ks = sm + pb * 8192;
        const u16* Vs = Ks + 4096;
        __syncthreads();                              // buf pb ready
        if (kt < 8) {                                 // prefetch kt+1 into buf pb^1
            u16* Kn = sm + (pb ^ 1) * 8192;
            u16* Vn = Kn + 4096;
            cp16(&Kg[(size_t)((kt + 1) * 64 + kinv0) * 64 + scol_sw], &Kn[srow * 64 + scol]);
            cp16(&Kg[(size_t)((kt + 1) * 64 + kinv1) * 64 + scol_sw], &Kn[(32 + srow) * 64 + scol]);
            cp16(&Vg[(size_t)srow * SEQ + (kt + 1) * 64 + scol_sw],        &Vn[srow * 64 + scol]);
            cp16(&Vg[(size_t)(32 + srow) * SEQ + (kt + 1) * 64 + scol_sw], &Vn[(32 + srow) * 64 + scol]);
        }
        // S^T = K Q^T : rows = ki (kperm'd), cols = q; each kf read feeds 3 MFMAs
        f32x4 sacc[3][4];
#pragma unroll
        for (int j = 0; j < 4; ++j) {
            short8 kf0 = *(const short8*)&Ks[(j * 16 + l16) * 64 + cA];
            short8 kf1 = *(const short8*)&Ks[(j * 16 + l16) * 64 + cB];
#pragma unroll
            for (int G = 0; G < 3; ++G) {
                f32x4 z = {0.f, 0.f, 0.f, 0.f};
                z = mfma16(kf0, qf[G][0], z);
                sacc[G][j] = mfma16(kf1, qf[G][1], z);
            }
        }
        // fixed-max softmax; pack P to bf16 immediately (frees fp32 p regs)
        u32 pk[3][8];
#pragma unroll
        for (int G = 0; G < 3; ++G)
#pragma unroll
            for (int j = 0; j < 4; ++j) {
                float e0 = __builtin_amdgcn_exp2f(sacc[G][j][0]);
                float e1 = __builtin_amdgcn_exp2f(sacc[G][j][1]);
                float e2 = __builtin_amdgcn_exp2f(sacc[G][j][2]);
                float e3 = __builtin_amdgcn_exp2f(sacc[G][j][3]);
                lacc[G] += (e0 + e1) + (e2 + e3);
                pk[G][2 * j]     = pkbf(e0, e1);
                pk[G][2 * j + 1] = pkbf(e2, e3);
            }
        // PV: P already in B-frag order thanks to kperm; each vf read feeds 3 MFMAs
#pragma unroll
        for (int g = 0; g < 2; ++g) {
            const int cg = g ? cB : cA;
#pragma unroll
            for (int i = 0; i < 4; ++i) {
                short8 vf = *(const short8*)&Vs[(i * 16 + l16) * 64 + cg];
#pragma unroll
                for (int G = 0; G < 3; ++G) {
                    short8 pf;
                    u32* pw = (u32*)&pf;
                    pw[0] = pk[G][4 * g + 0];
                    pw[1] = pk[G][4 * g + 1];
                    pw[2] = pk[G][4 * g + 2];
                    pw[3] = pk[G][4 * g + 3];
                    o[G][i] = mfma16(vf, pf, o[G][i]);
                }
            }
        }
    }
    // reduce l across quads (lane's q = l16 within group)
    float linv[3];
#pragma unroll
    for (int G = 0; G < 3; ++G) {
        float lr = lacc[G];
        lr += __shfl_xor(lr, 16);
        lr += __shfl_xor(lr, 32);
        if (quad == 0) Lpart[((size_t)(c * 16 + pair)) * SEQ + qt * 192 + G * 64 + rA] = lr;
        linv[G] = 1.0f / lr;
    }
    const size_t orow = ((size_t)(c * 16 + pair)) * SEQ + qt * 192;

    // single merged bounce: 192 rows x 72 stride in the (now free) dbuf LDS
    __syncthreads();
#pragma unroll
    for (int G = 0; G < 3; ++G)
#pragma unroll
        for (int i = 0; i < 4; ++i) {
            uint2 pkv;
            pkv.x = pkbf(o[G][i][0] * linv[G], o[G][i][1] * linv[G]);
            pkv.y = pkbf(o[G][i][2] * linv[G], o[G][i][3] * linv[G]);
            *(uint2*)&sm[(G * 64 + rA) * 72 + i * 16 + quad * 4] = pkv;
        }
    __syncthreads();
#pragma unroll
    for (int it = 0; it < 6; ++it) {
        int v = it * 256 + t;
        int row = v >> 3, col = (v & 7) * 8;
        *(uint4*)&Opart[(orow + row) * 64 + col] = *(const uint4*)&sm[row * 72 + col];
    }
}

// ---------------- combine split-K partials -> At [B][2304][512] bf16
__global__ __launch_bounds__(256) void attn_combine(
        const u16* __restrict__ Opart, const float* __restrict__ Lpart,
        u16* __restrict__ At) {
    const int bid = blockIdx.x;
    const int pair = bid / 144, sb = bid % 144;
    const int tid = threadIdx.x;
    const int rl = tid >> 4, dg = tid & 15;
    const int s = sb * 16 + rl;
    const int b = pair >> 3, h = pair & 7;
    float wc[NCHUNK], L = 0.f;
#pragma unroll
    for (int c = 0; c < NCHUNK; ++c) {
        wc[c] = Lpart[(size_t)(c * 16 + pair) * SEQ + s];
        L += wc[c];
    }
    float invL = 1.0f / L;
    float acc[4] = {0.f, 0.f, 0.f, 0.f};
#pragma unroll
    for (int c = 0; c < NCHUNK; ++c) {
        ushort4 v = *(const ushort4*)&Opart[((size_t)(c * 16 + pair) * SEQ + s) * 64 + dg * 4];
        acc[0] += wc[c] * bf2f(v.x);
        acc[1] += wc[c] * bf2f(v.y);
        acc[2] += wc[c] * bf2f(v.z);
        acc[3] += wc[c] * bf2f(v.w);
    }
    uint2 outv;
    outv.x = pkbf(acc[0] * invL, acc[1] * invL);
    outv.y = pkbf(acc[2] * invL, acc[3] * invL);
    *(uint2*)&At[((size_t)b * SEQ + s) * ND + h * 64 + dg * 4] = outv;
}

// ---------------- output projection GEMM (NT), 64x64 tiles, dbuf async staging
__global__ __launch_bounds__(256) void gemm_out_kernel(
        const u16* __restrict__ Wob, const u16* __restrict__ At,
        const float* __restrict__ bo, float* __restrict__ out) {
    __shared__ __align__(16) u16 sm[2 * 8192];       // 32 KB: [buf][As|Bs], each 64x64
    const int n0 = blockIdx.x * 64;
    const int m0 = blockIdx.y * 64;
    const int b  = blockIdx.z;
    const int t = threadIdx.x;
    const int lane = t & 63, w = t >> 6;
    const int l16 = lane & 15, quad = lane >> 4;
    const int x7 = l16 & 7;
    const int srow = t >> 3, scol = (t & 7) * 8;
    const int scol_sw = ((t & 7) ^ (srow & 7)) * 8;
    const u16* Ab = At + (size_t)b * SEQ * ND;

    f32x4 acc[4] = {};

    {
        u16* As = sm; u16* Bs = sm + 4096;
#pragma unroll
        for (int it = 0; it < 2; ++it) {
            int r2 = it * 32 + srow;
            cp16(&Wob[(size_t)(m0 + r2) * 512 + scol_sw], &As[r2 * 64 + scol]);
            cp16(&Ab [(size_t)(n0 + r2) * 512 + scol_sw], &Bs[r2 * 64 + scol]);
        }
    }
    for (int kb = 0; kb < 512; kb += 64) {
        const int pb = (kb >> 6) & 1;
        const u16* As = sm + pb * 8192;
        const u16* Bs = As + 4096;
        __syncthreads();
        if (kb + 64 < 512) {
            u16* An = sm + (pb ^ 1) * 8192;
            u16* Bn = An + 4096;
#pragma unroll
            for (int it = 0; it < 2; ++it) {
                int r2 = it * 32 + srow;
                cp16(&Wob[(size_t)(m0 + r2) * 512 + kb + 64 + scol_sw], &An[r2 * 64 + scol]);
                cp16(&Ab [(size_t)(n0 + r2) * 512 + kb + 64 + scol_sw], &Bn[r2 * 64 + scol]);
            }
        }
#pragma unroll
        for (int kk = 0; kk < 2; ++kk) {
            const int co = ((kk * 4 + quad) ^ x7) * 8;
            short8 af[4];
#pragma unroll
            for (int i = 0; i < 4; ++i)
                af[i] = *(const short8*)&As[(i * 16 + l16) * 64 + co];
            short8 bfr = *(const short8*)&Bs[(w * 16 + l16) * 64 + co];
#pragma unroll
            for (int i = 0; i < 4; ++i)
                acc[i] = mfma16(af[i], bfr, acc[i]);
        }
    }
#pragma unroll
    for (int i = 0; i < 4; ++i) {
        int cbase = m0 + i * 16 + quad * 4;
        int s = n0 + w * 16 + l16;
#pragma unroll
        for (int r = 0; r < 4; ++r) {
            int cc = cbase + r;
            __builtin_nontemporal_store(acc[i][r] + bo[cc],
                                        &out[((size_t)(b * 512 + cc)) * SEQ + s]);
        }
    }
}

extern "C" void kernel_launch(void* const* d_in, const int* in_sizes, int n_in,
                              void* d_out, int out_size, void* d_ws, size_t ws_size,
                              hipStream_t stream) {
    const float* H  = (const float*)d_in[0];
    const float* Wq = (const float*)d_in[1];
    const float* bq = (const float*)d_in[2];
    const float* Wk = (const float*)d_in[3];
    const float* bk = (const float*)d_in[4];
    const float* Wv = (const float*)d_in[5];
    const float* bv = (const float*)d_in[6];
    const float* Wo = (const float*)d_in[7];
    const float* bo = (const float*)d_in[8];
    float* out = (float*)d_out;

    u16* ws    = (u16*)d_ws;
    u16* Wqkv  = ws;                                  // 1536*512
    u16* Wob   = Wqkv  + 1536 * 512;                  // 512*512
    u16* Xbf   = Wob   + 512 * 512;                   // 2*2304*512
    u16* Qb    = Xbf   + 2 * SEQ * CDIM;              // 16*2304*64
    u16* Kb    = Qb    + 2 * SEQ * ND;
    u16* Vb    = Kb    + 2 * SEQ * ND;
    u16* At    = Vb    + 2 * SEQ * ND;
    u16* Opart = At    + 2 * SEQ * ND;                // 64*2304*64
    float* Lpart = (float*)(Opart + NCHUNK * 16 * SEQ * 64);

    prep_kernel<<<3328, 256, 0, stream>>>(H, Wq, Wk, Wv, Wo, Wqkv, Wob, Xbf);
    gemm_qkv_kernel<<<dim3(18, 24, 2), 256, 0, stream>>>(Wqkv, Xbf, bq, bk, bv, Qb, Kb, Vb);
    attn_partial<<<dim3(192, NCHUNK), 256, 0, stream>>>(Qb, Kb, Vb, Opart, Lpart);
    attn_combine<<<2304, 256, 0, stream>>>(Opart, Lpart, At);
    gemm_out_kernel<<<dim3(36, 8, 2), 256, 0, stream>>>(Wob, At, bo, out);
}